// Round 1
// baseline (274.506 us; speedup 1.0000x reference)
//
#include <hip/hip_runtime.h>
#include <hip/hip_fp16.h>
#include <cmath>

#define NNODES 8192
#define NB 64
#define ND 5
#define MAXDEG 64
#define NBLK_T0 2048       // t0 part of t0fill: wave = one node (full 2 KB row)
#define NBLK_LAY 2048      // layers: 8192 waves = one per node, lane = batch b

// xl / xr layout: [node][b=64][hc=16] fp16 (2 KB/row). h (final, sparse): fp16 same.
// R13: layer wave = one node v, lane = b (all 64 batches). Each lane reads the
// full 32 B hc-slice of a row (2x float4) -> one neighbor row = one contiguous
// 2 KB burst (2 wave-instructions) instead of 4x 512 B requests from 4 separate
// quarter-waves. Softmax AND the next-layer 16x16 projection are fully
// lane-local (the 16 shuffles of R11 are gone). Stores stay coalesced 2 KB rows.
// Gather bytes unchanged (already minimal: edges x 2 KB); this attacks the
// per-granule service rate (~3.4 TB/s at 512 B scattered), not traffic.

// ---------------- fused t0 + edge fill + needed mask ----------------

__global__ void __launch_bounds__(256)
k_t0fill(const float* __restrict__ x, const float* __restrict__ Wl0, const float* __restrict__ Wr0,
         __half* __restrict__ xl0, __half* __restrict__ xr0,
         const int* __restrict__ agent, const int* __restrict__ nbr,
         int* __restrict__ cnt, int* __restrict__ slot, int* __restrict__ needed) {
  if (blockIdx.x >= NBLK_T0) {
    int eb = blockIdx.x - NBLK_T0;
    if (eb < 160) {
      int i = eb*256 + threadIdx.x;                     // 40960 edges
      int v = nbr[i];
      int pos = atomicAdd(&cnt[v], 1);                  // cnt zeroed by memset
      slot[v*MAXDEG + 1 + pos] = i/ND;                  // src node u; row 0 = self
    } else if (threadIdx.x < NB) {
      int an = agent[threadIdx.x];
      needed[an] = 1;
      #pragma unroll
      for (int d = 0; d < ND; ++d) needed[nbr[an*ND + d]] = 1;
    }
    return;
  }
  int gid = blockIdx.x*blockDim.x + threadIdx.x;
  int n = gid >> 6;
  int b = gid & 63;
  const float4* src = (const float4*)(x + (((size_t)b*NNODES + n) << 4));
  float hv[16];
  #pragma unroll
  for (int q = 0; q < 4; ++q) *(float4*)(hv+4*q) = src[q];
  float yl[16], yr[16];
  #pragma unroll
  for (int j = 0; j < 16; ++j) { yl[j] = 0.f; yr[j] = 0.f; }
  #pragma unroll
  for (int f = 0; f < 16; ++f) {
    float hf = hv[f];
    #pragma unroll
    for (int j = 0; j < 16; ++j) {
      yl[j] = fmaf(hf, Wl0[f*16+j], yl[j]);
      yr[j] = fmaf(hf, Wr0[f*16+j], yr[j]);
    }
  }
  size_t idx = ((size_t)n << 10) + (b << 4);
  __half2 lh[8], rh[8];
  #pragma unroll
  for (int j = 0; j < 8; ++j) {
    lh[j] = __floats2half2_rn(yl[2*j], yl[2*j+1]);
    rh[j] = __floats2half2_rn(yr[2*j], yr[2*j+1]);
  }
  float4* ld = (float4*)(xl0 + idx);
  ld[0] = *(float4*)&lh[0]; ld[1] = *(float4*)&lh[4];
  float4* rd = (float4*)(xr0 + idx);
  rd[0] = *(float4*)&rh[0]; rd[1] = *(float4*)&rh[4];
}

// ---------------- GATv2 layer: one wave per node, lane = batch ----------------
// sW: [0,256) WlNext, [256,512) WrNext, [512,528) att, [528,544) bias

struct Row { float4 c0, c1; };   // 32 B = 16 halves: heads 0-1 in c0, 2-3 in c1

template<bool LAST>
__global__ void __launch_bounds__(256)
k_layer(const __half* __restrict__ xlin, const __half* __restrict__ xrin,
        __half* __restrict__ xlout, __half* __restrict__ xrout,
        const float* __restrict__ WlNext, const float* __restrict__ WrNext,
        const float* __restrict__ att, const float* __restrict__ bias,
        const int* __restrict__ cnt, const int* __restrict__ slot,
        const int* __restrict__ needed, __half* __restrict__ h,
        float* __restrict__ meanpart) {
  __shared__ float sW[544];
  int tid = threadIdx.x;
  int w = tid >> 6, lane = tid & 63;

  if (!LAST) {
    sW[tid]     = WlNext[tid];                   // 256 threads, 256 floats each
    sW[256+tid] = WrNext[tid];
  }
  if (tid < 16)      sW[512+tid]    = att[tid];
  else if (tid < 32) sW[512+tid]    = bias[tid-16];   // lands at 528+
  __syncthreads();

  int v = (blockIdx.x << 2) + w;                 // node; lane = batch b
  size_t loff = (size_t)(lane << 4);             // halves offset within row (32 B)

  float aw[16];
  #pragma unroll
  for (int k = 0; k < 16; ++k) aw[k] = sW[512+k];   // LDS broadcast, once

  // self xr row (full 16 hc for this b)
  float xrf[16];
  {
    const float4* p = (const float4*)(xrin + (((size_t)v) << 10) + loff);
    float4 c0 = p[0], c1 = p[1];
    __half2* ph0 = (__half2*)&c0;
    __half2* ph1 = (__half2*)&c1;
    #pragma unroll
    for (int j = 0; j < 4; ++j) {
      float2 f0 = __half22float2(ph0[j]);
      xrf[2*j]   = f0.x; xrf[2*j+1]   = f0.y;
      float2 f1 = __half22float2(ph1[j]);
      xrf[8+2*j] = f1.x; xrf[8+2*j+1] = f1.y;
    }
  }

  float s4[4] = {0.f, 0.f, 0.f, 0.f};
  float a[16];
  #pragma unroll
  for (int k = 0; k < 16; ++k) a[k] = 0.f;

  int deg = cnt[v];
  int tot = deg + 1;                             // + self (row 0 = v itself)
  const int* sl = slot + v*MAXDEG;               // sl[1..deg] valid

  auto loadrow = [&](int u) -> Row {
    const float4* p = (const float4*)(xlin + (((size_t)u) << 10) + loff);
    Row r; r.c0 = p[0]; r.c1 = p[1]; return r;
  };
  auto process = [&](Row r) {
    float t[16];
    __half2* ph0 = (__half2*)&r.c0;
    __half2* ph1 = (__half2*)&r.c1;
    #pragma unroll
    for (int j = 0; j < 4; ++j) {
      float2 f0 = __half22float2(ph0[j]);
      t[2*j]   = f0.x; t[2*j+1]   = f0.y;
      float2 f1 = __half22float2(ph1[j]);
      t[8+2*j] = f1.x; t[8+2*j+1] = f1.y;
    }
    #pragma unroll
    for (int hd = 0; hd < 4; ++hd) {
      float z0 = t[4*hd+0] + xrf[4*hd+0]; z0 = (z0 >= 0.f) ? z0 : 0.2f*z0;
      float z1 = t[4*hd+1] + xrf[4*hd+1]; z1 = (z1 >= 0.f) ? z1 : 0.2f*z1;
      float z2 = t[4*hd+2] + xrf[4*hd+2]; z2 = (z2 >= 0.f) ? z2 : 0.2f*z2;
      float z3 = t[4*hd+3] + xrf[4*hd+3]; z3 = (z3 >= 0.f) ? z3 : 0.2f*z3;
      float lg = fmaf(z0, aw[4*hd+0], fmaf(z1, aw[4*hd+1],
                 fmaf(z2, aw[4*hd+2], z3*aw[4*hd+3])));
      float p = __expf(lg);                      // no max-rescale: logits bounded
      s4[hd] += p;
      a[4*hd+0] = fmaf(p, t[4*hd+0], a[4*hd+0]);
      a[4*hd+1] = fmaf(p, t[4*hd+1], a[4*hd+1]);
      a[4*hd+2] = fmaf(p, t[4*hd+2], a[4*hd+2]);
      a[4*hd+3] = fmaf(p, t[4*hd+3], a[4*hd+3]);
    }
  };

  // straight-line prefetch of min(tot,4) rows + prefetched depth-2 remainder
  Row r0, r1, r2, r3, pA, pB;
  r0 = loadrow(v);
  if (tot > 1) r1 = loadrow(sl[1]);
  if (tot > 2) r2 = loadrow(sl[2]);
  if (tot > 3) r3 = loadrow(sl[3]);
  if (tot > 4) pA = loadrow(sl[4]);
  if (tot > 5) pB = loadrow(sl[5]);
  process(r0);
  if (tot > 1) process(r1);
  if (tot > 2) process(r2);
  if (tot > 3) process(r3);
  int e = 4;
  for (; e+1 < tot; e += 2) {
    Row cA = pA; if (e+2 < tot) pA = loadrow(sl[e+2]);
    Row cB = pB; if (e+3 < tot) pB = loadrow(sl[e+3]);
    process(cA); process(cB);
  }
  if (e < tot) process(pA);

  float o[16];
  #pragma unroll
  for (int hd = 0; hd < 4; ++hd) {
    float inv = 1.f / s4[hd];
    #pragma unroll
    for (int k = 0; k < 4; ++k)
      o[4*hd+k] = fmaf(a[4*hd+k], inv, sW[528+4*hd+k]);
  }

  if (!LAST) {
    // next-layer projection: fully lane-local (lane holds all 16 hc of its b)
    float yl[16], yr[16];
    #pragma unroll
    for (int j = 0; j < 16; ++j) { yl[j] = 0.f; yr[j] = 0.f; }
    #pragma unroll
    for (int f = 0; f < 16; ++f) {
      float ofv = o[f];
      #pragma unroll
      for (int j4 = 0; j4 < 4; ++j4) {
        float4 wl4 = *(float4*)&sW[f*16 + j4*4];        // broadcast: conflict-free
        float4 wr4 = *(float4*)&sW[256 + f*16 + j4*4];
        yl[j4*4+0] = fmaf(ofv, wl4.x, yl[j4*4+0]);
        yl[j4*4+1] = fmaf(ofv, wl4.y, yl[j4*4+1]);
        yl[j4*4+2] = fmaf(ofv, wl4.z, yl[j4*4+2]);
        yl[j4*4+3] = fmaf(ofv, wl4.w, yl[j4*4+3]);
        yr[j4*4+0] = fmaf(ofv, wr4.x, yr[j4*4+0]);
        yr[j4*4+1] = fmaf(ofv, wr4.y, yr[j4*4+1]);
        yr[j4*4+2] = fmaf(ofv, wr4.z, yr[j4*4+2]);
        yr[j4*4+3] = fmaf(ofv, wr4.w, yr[j4*4+3]);
      }
    }
    __half2 lh[8], rh[8];
    #pragma unroll
    for (int j = 0; j < 8; ++j) {
      lh[j] = __floats2half2_rn(yl[2*j], yl[2*j+1]);
      rh[j] = __floats2half2_rn(yr[2*j], yr[2*j+1]);
    }
    size_t idx = (((size_t)v) << 10) + loff;
    float4* ld = (float4*)(xlout + idx);
    ld[0] = *(float4*)&lh[0]; ld[1] = *(float4*)&lh[4];
    float4* rd = (float4*)(xrout + idx);
    rd[0] = *(float4*)&rh[0]; rd[1] = *(float4*)&rh[4];
  } else {
    if (needed[v]) {                             // sparse h: agent/neighbor rows only
      __half2 hh[8];
      #pragma unroll
      for (int j = 0; j < 8; ++j) hh[j] = __floats2half2_rn(o[2*j], o[2*j+1]);
      float4* hd = (float4*)(h + (((size_t)v) << 10) + loff);
      hd[0] = *(float4*)&hh[0]; hd[1] = *(float4*)&hh[4];
    }
    // block partial mean: msm[w][hc][b], conflict-free both directions
    __shared__ float msm[4][16][64];
    #pragma unroll
    for (int k = 0; k < 16; ++k) msm[w][k][lane] = o[k];
    __syncthreads();
    #pragma unroll
    for (int c = 0; c < 4; ++c) {
      int hc = c*4 + w;
      int b  = lane;
      float ssum = msm[0][hc][b] + msm[1][hc][b] + msm[2][hc][b] + msm[3][hc][b];
      meanpart[(size_t)blockIdx.x*1024 + hc*64 + b] = ssum;   // coalesced
    }
  }
}

// ---------------- fused tail: meanpart reduce + mean MLP + edge MLP ----------------

__global__ void __launch_bounds__(256)
k_tail(const __half* __restrict__ h, const int* __restrict__ agent,
       const int* __restrict__ nbr, const float* __restrict__ meanpart,
       const float* __restrict__ Wg1, const float* __restrict__ bg1,
       const float* __restrict__ Wg2, const float* __restrict__ bg2,
       const float* __restrict__ We1, const float* __restrict__ be1,
       const float* __restrict__ We2, const float* __restrict__ be2,
       const float* __restrict__ We3, const float* __restrict__ be3,
       float* __restrict__ out) {
  int b = blockIdx.x;
  int t = threadIdx.x;                 // 256
  __shared__ float red[256];
  __shared__ float mean[16], g1[32], aggs[64];
  __shared__ float srcv[16];
  __shared__ float tgt[5][16];
  __shared__ float e1s[15][16];
  __shared__ float e2s[15][8];
  int an = agent[b];

  // reduce this b's partials over all 2048 layer blocks: meanpart[blk][hc][b]
  {
    int hc = t & 15, grp = t >> 4;     // 16 groups x 128 blocks
    float s = 0.f;
    int base = grp*128;
    for (int p = 0; p < 128; ++p)
      s += meanpart[(size_t)(base+p)*1024 + hc*64 + b];
    red[t] = s;
    __syncthreads();
    if (t < 16) {
      float m = 0.f;
      for (int g = 0; g < 16; ++g) m += red[g*16 + t];
      mean[t] = m * (1.0f/NNODES);
    }
  }
  if (t >= 64 && t < 80) srcv[t-64] = __half2float(h[((size_t)an << 10) + (b << 4) + (t-64)]);
  if (t >= 96 && t < 176) {
    int d = (t-96)/16, k = (t-96)%16;
    int nn = nbr[an*ND + d];
    tgt[d][k] = __half2float(h[((size_t)nn << 10) + (b << 4) + k]);
  }
  __syncthreads();
  if (t < 32) {
    float a = bg1[t];
    for (int f = 0; f < 16; ++f) a = fmaf(mean[f], Wg1[f*32+t], a);
    g1[t] = tanhf(a);
  }
  __syncthreads();
  if (t < 64) {
    float a = bg2[t];
    for (int f = 0; f < 32; ++f) a = fmaf(g1[f], Wg2[f*64+t], a);
    aggs[t] = tanhf(a);
  }
  __syncthreads();
  if (t < 240) {
    int j = t & 15, td = t >> 4;       // td = tk*5+d
    int tk = td/5, d = td%5;
    float a = be1[j];
    for (int k = 0; k < 16; ++k) a = fmaf(srcv[k],  We1[k*16+j],      a);
    a += We1[(16+tk)*16 + j];          // one-hot token rows 16..18
    for (int k = 0; k < 16; ++k) a = fmaf(tgt[d][k], We1[(19+k)*16+j], a);
    for (int k = 0; k < 64; ++k) a = fmaf(aggs[k],  We1[(35+k)*16+j], a);
    e1s[td][j] = tanhf(a);
  }
  __syncthreads();
  if (t < 120) {
    int j = t & 7, td = t >> 3;
    float a = be2[j];
    for (int k = 0; k < 16; ++k) a = fmaf(e1s[td][k], We2[k*8+j], a);
    e2s[td][j] = tanhf(a);
  }
  __syncthreads();
  if (t < 15) {
    float a = be3[0];
    for (int k = 0; k < 8; ++k) a = fmaf(e2s[t][k], We3[k], a);
    out[b*15 + t] = a;
  }
}

// ---------------- launch ----------------

extern "C" void kernel_launch(void* const* d_in, const int* in_sizes, int n_in,
                              void* d_out, int out_size, void* d_ws, size_t ws_size,
                              hipStream_t stream) {
  const float* x     = (const float*)d_in[0];
  const int*   agent = (const int*)  d_in[1];
  const int*   nbr   = (const int*)  d_in[2];
  const float* Wl    = (const float*)d_in[3];   // (4,16,4,4)
  const float* Wr    = (const float*)d_in[4];
  const float* att   = (const float*)d_in[5];   // (4,4,4)
  const float* bias  = (const float*)d_in[6];   // (4,16)
  const float* Wg1   = (const float*)d_in[7];
  const float* bg1   = (const float*)d_in[8];
  const float* Wg2   = (const float*)d_in[9];
  const float* bg2   = (const float*)d_in[10];
  const float* We1   = (const float*)d_in[11];
  const float* be1   = (const float*)d_in[12];
  const float* We2   = (const float*)d_in[13];
  const float* be2   = (const float*)d_in[14];
  const float* We3   = (const float*)d_in[15];
  const float* be3   = (const float*)d_in[16];
  float* out = (float*)d_out;

  char* ws = (char*)d_ws;
  size_t off = 0;
  auto alloc = [&](size_t bytes) -> void* {
    void* p = ws + off;
    off += (bytes + 255) & ~(size_t)255;
    return p;
  };
  const size_t XBYTES = (size_t)NNODES*NB*16*sizeof(__half);    // 16 MB
  __half* h    = (__half*)alloc(XBYTES);
  __half* xlA  = (__half*)alloc(XBYTES);
  __half* xlB  = (__half*)alloc(XBYTES);
  __half* xrA  = (__half*)alloc(XBYTES);
  __half* xrB  = (__half*)alloc(XBYTES);
  int*  slot   = (int*)alloc((size_t)NNODES*MAXDEG*sizeof(int));
  float* meanpart = (float*)alloc((size_t)NBLK_LAY*1024*sizeof(float));  // 8 MB
  // cnt | needed: contiguous, zeroed by one memset
  int* cnt    = (int*)alloc(NNODES*sizeof(int));
  int* needed = (int*)alloc(NNODES*sizeof(int));

  hipMemsetAsync(cnt, 0, NNODES*sizeof(int)*2, stream);

  k_t0fill<<<NBLK_T0 + 161, 256, 0, stream>>>(x, Wl, Wr, xlA, xrA,
                                              agent, nbr, cnt, slot, needed);

  k_layer<false><<<NBLK_LAY, 256, 0, stream>>>(xlA, xrA, xlB, xrB, Wl + 256, Wr + 256,
                                               att,      bias,      cnt, slot, needed, nullptr, nullptr);
  k_layer<false><<<NBLK_LAY, 256, 0, stream>>>(xlB, xrB, xlA, xrA, Wl + 512, Wr + 512,
                                               att + 16, bias + 16, cnt, slot, needed, nullptr, nullptr);
  k_layer<false><<<NBLK_LAY, 256, 0, stream>>>(xlA, xrA, xlB, xrB, Wl + 768, Wr + 768,
                                               att + 32, bias + 32, cnt, slot, needed, nullptr, nullptr);
  k_layer<true ><<<NBLK_LAY, 256, 0, stream>>>(xlB, xrB, nullptr, nullptr, nullptr, nullptr,
                                               att + 48, bias + 48, cnt, slot, needed, h, meanpart);

  k_tail<<<NB, 256, 0, stream>>>(h, agent, nbr, meanpart,
                                 Wg1, bg1, Wg2, bg2,
                                 We1, be1, We2, be2, We3, be3, out);
}